// Round 1
// baseline (3900.656 us; speedup 1.0000x reference)
//
#include <hip/hip_runtime.h>
#include <hip/hip_bf16.h>
#include <math.h>

#define N_   2048
#define SEQ_ 128
#define E_   512
#define R_   128
#define TC   16   // t-rows per chunk

// One block per n, 128 threads (thread = output channel r).
__global__ __launch_bounds__(128)
void mlp_kernel(const int* __restrict__ C, const float* __restrict__ L,
                const float* __restrict__ Pw, const float* __restrict__ Nw,
                const float* __restrict__ W1p, const float* __restrict__ b1p,
                const float* __restrict__ W2p, const float* __restrict__ b2p,
                const float* __restrict__ W1n, const float* __restrict__ b1n,
                const float* __restrict__ W2n, const float* __restrict__ b2n,
                const float* __restrict__ Wa,  const float* __restrict__ ba,
                float* __restrict__ pos_t, float* __restrict__ neg_t,
                float* __restrict__ ff)
{
    const int n = blockIdx.x;
    const int r = threadIdx.x;           // 0..127

    __shared__ __align__(16) float sL[TC][E_];     // 32 KB
    __shared__ __align__(16) float sh1p[TC][R_];   // 8 KB
    __shared__ __align__(16) float sh1n[TC][R_];   // 8 KB
    __shared__ float sPm[TC], sNm[TC];

    const int c0 = C[2 * n], c1 = C[2 * n + 1];

    const float bb1p = b1p[r], bb2p = b2p[r];
    const float bb1n = b1n[r], bb2n = b2n[r];
    const float bba  = ba[r];

    float accP = 0.f, accN = 0.f, accA = 0.f;

    for (int t0 = 0; t0 < SEQ_; t0 += TC) {
        // ---- stage TC rows of L into LDS (coalesced float4) ----
        const float4* L4 = (const float4*)(L + ((size_t)n * SEQ_ + t0) * E_);
        float4* sL4 = (float4*)&sL[0][0];
#pragma unroll
        for (int i = 0; i < (TC * E_ / 4) / 128; ++i)
            sL4[i * 128 + r] = L4[i * 128 + r];
        if (r < TC) {
            const int t = t0 + r;
            const bool in = (t >= c0) && (t <= c1);
            sPm[r] = in ? Pw[n * SEQ_ + t] : 0.f;
            sNm[r] = in ? 0.f : Nw[n * SEQ_ + t];
        }
        __syncthreads();

        // ---- layer 1: raw dots (mask factored out — it is a per-(n,t) scalar) ----
        float dP[TC], dN[TC], dA[TC];
#pragma unroll
        for (int tt = 0; tt < TC; ++tt) { dP[tt] = 0.f; dN[tt] = 0.f; dA[tt] = 0.f; }

        for (int e4 = 0; e4 < E_ / 4; ++e4) {
            const int e = e4 * 4;
            float w1[4], w2[4], w3[4];
#pragma unroll
            for (int j = 0; j < 4; ++j) {
                w1[j] = W1p[(e + j) * R_ + r];
                w2[j] = W1n[(e + j) * R_ + r];
                w3[j] = Wa [(e + j) * R_ + r];
            }
#pragma unroll
            for (int tt = 0; tt < TC; ++tt) {
                const float4 x = *(const float4*)&sL[tt][e];
                dP[tt] = fmaf(x.x, w1[0], dP[tt]);
                dP[tt] = fmaf(x.y, w1[1], dP[tt]);
                dP[tt] = fmaf(x.z, w1[2], dP[tt]);
                dP[tt] = fmaf(x.w, w1[3], dP[tt]);
                dN[tt] = fmaf(x.x, w2[0], dN[tt]);
                dN[tt] = fmaf(x.y, w2[1], dN[tt]);
                dN[tt] = fmaf(x.z, w2[2], dN[tt]);
                dN[tt] = fmaf(x.w, w2[3], dN[tt]);
                dA[tt] = fmaf(x.x, w3[0], dA[tt]);
                dA[tt] = fmaf(x.y, w3[1], dA[tt]);
                dA[tt] = fmaf(x.z, w3[2], dA[tt]);
                dA[tt] = fmaf(x.w, w3[3], dA[tt]);
            }
        }

#pragma unroll
        for (int tt = 0; tt < TC; ++tt) {
            const float pm = sPm[tt], nm = sNm[tt];
            sh1p[tt][r] = tanhf(fmaf(pm, dP[tt], bb1p));
            sh1n[tt][r] = tanhf(fmaf(nm, dN[tt], bb1n));
            accA += tanhf(fmaf(pm + nm, dA[tt], bba));
        }
        __syncthreads();

        // ---- layer 2 ----
        float e2p[TC], e2n[TC];
#pragma unroll
        for (int tt = 0; tt < TC; ++tt) { e2p[tt] = 0.f; e2n[tt] = 0.f; }

        for (int k4 = 0; k4 < R_ / 4; ++k4) {
            const int k = k4 * 4;
            float w2p[4], w2n[4];
#pragma unroll
            for (int j = 0; j < 4; ++j) {
                w2p[j] = W2p[(k + j) * R_ + r];
                w2n[j] = W2n[(k + j) * R_ + r];
            }
#pragma unroll
            for (int tt = 0; tt < TC; ++tt) {
                const float4 hp = *(const float4*)&sh1p[tt][k];
                const float4 hn = *(const float4*)&sh1n[tt][k];
                e2p[tt] = fmaf(hp.x, w2p[0], e2p[tt]);
                e2p[tt] = fmaf(hp.y, w2p[1], e2p[tt]);
                e2p[tt] = fmaf(hp.z, w2p[2], e2p[tt]);
                e2p[tt] = fmaf(hp.w, w2p[3], e2p[tt]);
                e2n[tt] = fmaf(hn.x, w2n[0], e2n[tt]);
                e2n[tt] = fmaf(hn.y, w2n[1], e2n[tt]);
                e2n[tt] = fmaf(hn.z, w2n[2], e2n[tt]);
                e2n[tt] = fmaf(hn.w, w2n[3], e2n[tt]);
            }
        }

#pragma unroll
        for (int tt = 0; tt < TC; ++tt) {
            accP += tanhf(e2p[tt] + bb2p);
            accN += tanhf(e2n[tt] + bb2n);
        }
        __syncthreads();   // protect sL/sh1 before next chunk overwrites
    }

    const float inv = 1.0f / (float)SEQ_;
    pos_t[n * R_ + r] = accP * inv;
    neg_t[n * R_ + r] = accN * inv;
    ff[n * R_ + r]    = accA * inv;
}

// Pairwise exp(-dist) sums. Block handles 16 i-rows; 256 threads = 16x16 pair tile.
__global__ __launch_bounds__(256)
void sim_kernel(const float* __restrict__ pos_t, const float* __restrict__ neg_t,
                double* __restrict__ sims)
{
    __shared__ float sPi[16][R_ + 1];
    __shared__ float sPj[16][R_ + 1];
    __shared__ float sNj[16][R_ + 1];

    const int ib  = blockIdx.x;          // 0..127
    const int tid = threadIdx.x;
    const int ti  = tid >> 4, tj = tid & 15;

    for (int idx = tid; idx < 16 * R_; idx += 256) {
        const int row = idx >> 7, col = idx & 127;
        sPi[row][col] = pos_t[(ib * 16 + row) * R_ + col];
    }

    float sumP = 0.f, sumN = 0.f;
    for (int jb = 0; jb < N_ / 16; ++jb) {
        __syncthreads();
        for (int idx = tid; idx < 16 * R_; idx += 256) {
            const int row = idx >> 7, col = idx & 127;
            sPj[row][col] = pos_t[(jb * 16 + row) * R_ + col];
            sNj[row][col] = neg_t[(jb * 16 + row) * R_ + col];
        }
        __syncthreads();

        float d2p = 0.f, d2n = 0.f;
#pragma unroll 8
        for (int rr = 0; rr < R_; ++rr) {
            const float xi = sPi[ti][rr];
            const float dp = xi - sPj[tj][rr];
            const float dn = xi - sNj[tj][rr];
            d2p = fmaf(dp, dp, d2p);
            d2n = fmaf(dn, dn, d2n);
        }
        sumP += expf(-sqrtf(d2p));
        sumN += expf(-sqrtf(d2n));
    }

    // wave (64-lane) reduce, then cross-wave via LDS
#pragma unroll
    for (int off = 32; off; off >>= 1) {
        sumP += __shfl_down(sumP, off);
        sumN += __shfl_down(sumN, off);
    }
    __shared__ double redP[4], redN[4];
    const int wave = tid >> 6, lane = tid & 63;
    if (lane == 0) { redP[wave] = (double)sumP; redN[wave] = (double)sumN; }
    __syncthreads();
    if (tid == 0) {
        atomicAdd(&sims[0], redP[0] + redP[1] + redP[2] + redP[3]);
        atomicAdd(&sims[1], redN[0] + redN[1] + redN[2] + redN[3]);
    }
}

__global__ void init_kernel(double* __restrict__ sims)
{
    if (threadIdx.x < 2) sims[threadIdx.x] = 0.0;
}

__global__ void finalize_kernel(const double* __restrict__ sims, float* __restrict__ out)
{
    out[N_ * R_] = (float)(-log(sims[0] / sims[1]));
}

extern "C" void kernel_launch(void* const* d_in, const int* in_sizes, int n_in,
                              void* d_out, int out_size, void* d_ws, size_t ws_size,
                              hipStream_t stream)
{
    const int*   C   = (const int*)  d_in[0];
    const float* L   = (const float*)d_in[1];
    const float* Pw  = (const float*)d_in[2];
    const float* Nw  = (const float*)d_in[3];
    const float* W1p = (const float*)d_in[4];
    const float* b1p = (const float*)d_in[5];
    const float* W2p = (const float*)d_in[6];
    const float* b2p = (const float*)d_in[7];
    const float* W1n = (const float*)d_in[8];
    const float* b1n = (const float*)d_in[9];
    const float* W2n = (const float*)d_in[10];
    const float* b2n = (const float*)d_in[11];
    const float* Wa  = (const float*)d_in[12];
    const float* ba  = (const float*)d_in[13];

    float* out = (float*)d_out;                 // [N*R feature | 1 loss]
    float* pos_t = (float*)d_ws;                // N*R floats
    float* neg_t = pos_t + N_ * R_;             // N*R floats
    double* sims = (double*)(neg_t + N_ * R_);  // 2 doubles (8B-aligned: 2MB offset)

    hipLaunchKernelGGL(init_kernel, dim3(1), dim3(64), 0, stream, sims);
    hipLaunchKernelGGL(mlp_kernel, dim3(N_), dim3(128), 0, stream,
                       C, L, Pw, Nw, W1p, b1p, W2p, b2p,
                       W1n, b1n, W2n, b2n, Wa, ba, pos_t, neg_t, out);
    hipLaunchKernelGGL(sim_kernel, dim3(N_ / 16), dim3(256), 0, stream,
                       pos_t, neg_t, sims);
    hipLaunchKernelGGL(finalize_kernel, dim3(1), dim3(1), 0, stream, sims, out);
}

// Round 2
// 1170.199 us; speedup vs baseline: 3.3333x; 3.3333x over previous
//
#include <hip/hip_runtime.h>
#include <math.h>

#define N_   2048
#define SEQ_ 128
#define E_   512
#define R_   128

typedef __attribute__((ext_vector_type(8))) short short8;
typedef __attribute__((ext_vector_type(4))) float f32x4;

__device__ __forceinline__ ushort f2bf(float f) {
    union { float f; uint u; } v; v.f = f;
    uint r = v.u + 0x7FFFu + ((v.u >> 16) & 1u);   // RNE
    return (ushort)(r >> 16);
}
__device__ __forceinline__ float fast_tanhf(float x) {
    float ax = fabsf(x);
    float t = __expf(-2.f * ax);
    float r = (1.f - t) / (1.f + t);
    return copysignf(r, x);
}

// ---- prep: transpose weights to [r][k] bf16 so MFMA B-frags are k-contiguous ----
__global__ void prep_kernel(const float* __restrict__ W1p, const float* __restrict__ W1n,
                            const float* __restrict__ Wa,  const float* __restrict__ W2p,
                            const float* __restrict__ W2n, ushort* __restrict__ WT)
{
    int idx = blockIdx.x * 256 + threadIdx.x;      // 0..229375
    if (idx < 196608) {                            // three E x R mats -> [128][512]
        int m = idx >> 16;
        int o = idx & 65535;
        int r = o >> 9, e = o & 511;
        const float* src = (m == 0) ? W1p : (m == 1) ? W1n : Wa;
        WT[idx] = f2bf(src[e * R_ + r]);
    } else if (idx < 229376) {                     // two R x R mats -> [128][128]
        int o = idx - 196608;
        int m = o >> 14;
        int p = o & 16383;
        int r = p >> 7, e = p & 127;
        const float* src = (m == 0) ? W2p : W2n;
        WT[idx] = f2bf(src[e * R_ + r]);
    }
}

#define SXP 72    // padded row stride (64+8) bf16
#define SWP 72
#define H1P 136   // padded row stride (128+8) bf16

// One block per n. 4 waves; wave w computes all 128 t-rows x 32 r-cols (r in [32w,32w+32)).
__global__ __launch_bounds__(256, 2)
void mlp_mfma_kernel(const int* __restrict__ C, const float* __restrict__ L,
                     const float* __restrict__ Pw, const float* __restrict__ Nw,
                     const float* __restrict__ b1p, const float* __restrict__ b2p,
                     const float* __restrict__ b1n, const float* __restrict__ b2n,
                     const float* __restrict__ ba,  const ushort* __restrict__ WT,
                     float* __restrict__ pos_t, float* __restrict__ neg_t,
                     float* __restrict__ ff)
{
    __shared__ __align__(16) ushort ldsU[36864];   // 72 KB, phase-aliased
    __shared__ float sPm[SEQ_], sNm[SEQ_];

    ushort* sX = ldsU;                 // phase1: [128][SXP]
    ushort* sW = ldsU + 9216;          // phase1: [3][128][SWP]
    ushort* sH1 = ldsU;                // phase2: [128][H1P]
    ushort* sW2 = ldsU + 17408;        // phase2: [128][H1P]

    const ushort* W1pT = WT;
    const ushort* W1nT = WT + 65536;
    const ushort* WaT  = WT + 131072;
    const ushort* W2pT = WT + 196608;
    const ushort* W2nT = WT + 212992;

    const int n = blockIdx.x;
    const int tid = threadIdx.x;
    const int w = tid >> 6, l = tid & 63, q = l >> 4, c = l & 15;

    if (tid < SEQ_) {
        int c0 = C[2 * n], c1 = C[2 * n + 1];
        bool in = (tid >= c0) && (tid <= c1);
        sPm[tid] = in ? Pw[n * SEQ_ + tid] : 0.f;
        sNm[tid] = in ? 0.f : Nw[n * SEQ_ + tid];
    }

    f32x4 accP[8][2], accN[8][2], accA[8][2];
#pragma unroll
    for (int mt = 0; mt < 8; ++mt)
#pragma unroll
        for (int nt = 0; nt < 2; ++nt) { accP[mt][nt] = 0.f; accN[mt][nt] = 0.f; accA[mt][nt] = 0.f; }

    const float* Lbase = L + (size_t)n * SEQ_ * E_;

    for (int ch = 0; ch < 8; ++ch) {
        const int kb = ch * 64;
        // stage X chunk (128 t x 64 e), fp32 -> bf16
#pragma unroll
        for (int it = 0; it < 8; ++it) {
            int idx = it * 256 + tid;            // 2048 float4
            int row = idx >> 4, seg = idx & 15;
            float4 v = *(const float4*)(Lbase + row * E_ + kb + seg * 4);
            ushort4 h;
            h.x = f2bf(v.x); h.y = f2bf(v.y); h.z = f2bf(v.z); h.w = f2bf(v.w);
            *(ushort4*)&sX[row * SXP + seg * 4] = h;
        }
        // stage W chunks for 3 sets: rows of W^T (k-contiguous)
#pragma unroll
        for (int s = 0; s < 3; ++s) {
            const ushort* Wsrc = (s == 0) ? W1pT : (s == 1) ? W1nT : WaT;
#pragma unroll
            for (int it = 0; it < 4; ++it) {
                int idx = it * 256 + tid;        // 1024 x 16B
                int row = idx >> 3, seg = idx & 7;
                short8 v = *(const short8*)(Wsrc + row * E_ + kb + seg * 8);
                *(short8*)&sW[(s * 128 + row) * SWP + seg * 8] = v;
            }
        }
        __syncthreads();

#pragma unroll
        for (int k2 = 0; k2 < 2; ++k2) {
            const int ko = k2 * 32 + q * 8;
            short8 a[8];
#pragma unroll
            for (int mt = 0; mt < 8; ++mt)
                a[mt] = *(const short8*)&sX[(mt * 16 + c) * SXP + ko];
#pragma unroll
            for (int nt = 0; nt < 2; ++nt) {
                const int r = w * 32 + nt * 16 + c;
                short8 bP = *(const short8*)&sW[(0 * 128 + r) * SWP + ko];
                short8 bN = *(const short8*)&sW[(1 * 128 + r) * SWP + ko];
                short8 bA = *(const short8*)&sW[(2 * 128 + r) * SWP + ko];
#pragma unroll
                for (int mt = 0; mt < 8; ++mt) {
                    accP[mt][nt] = __builtin_amdgcn_mfma_f32_16x16x32_bf16(a[mt], bP, accP[mt][nt], 0, 0, 0);
                    accN[mt][nt] = __builtin_amdgcn_mfma_f32_16x16x32_bf16(a[mt], bN, accN[mt][nt], 0, 0, 0);
                    accA[mt][nt] = __builtin_amdgcn_mfma_f32_16x16x32_bf16(a[mt], bA, accA[mt][nt], 0, 0, 0);
                }
            }
        }
        __syncthreads();
    }

    // ---- A-set epilogue -> final_feature ----
#pragma unroll
    for (int nt = 0; nt < 2; ++nt) {
        int r = w * 32 + nt * 16 + c;
        float bar = ba[r];
        float s = 0.f;
#pragma unroll
        for (int mt = 0; mt < 8; ++mt)
#pragma unroll
            for (int i = 0; i < 4; ++i) {
                int t = mt * 16 + q * 4 + i;
                float m = sPm[t] + sNm[t];          // in-region ? Pw : Nw
                s += fast_tanhf(fmaf(m, accA[mt][nt][i], bar));
            }
        s += __shfl_xor(s, 16);
        s += __shfl_xor(s, 32);
        if (q == 0) ff[n * R_ + r] = s * (1.f / SEQ_);
    }

    // ---- P then N: mask+bias+tanh -> H1 (LDS) -> layer-2 MFMA -> mean ----
    for (int ps = 0; ps < 2; ++ps) {
        const f32x4 (*acc1)[2] = ps ? accN : accP;
        const float* sM  = ps ? sNm : sPm;
        const float* b1  = ps ? b1n : b1p;
        const float* b2  = ps ? b2n : b2p;
        const ushort* W2T = ps ? W2nT : W2pT;
        float* outp = ps ? neg_t : pos_t;

        __syncthreads();   // previous phase readers done before ldsU reuse
#pragma unroll
        for (int nt = 0; nt < 2; ++nt) {
            int r = w * 32 + nt * 16 + c;
            float b1r = b1[r];
#pragma unroll
            for (int mt = 0; mt < 8; ++mt)
#pragma unroll
                for (int i = 0; i < 4; ++i) {
                    int t = mt * 16 + q * 4 + i;
                    float h = fast_tanhf(fmaf(sM[t], acc1[mt][nt][i], b1r));
                    sH1[t * H1P + r] = f2bf(h);
                }
        }
#pragma unroll
        for (int it = 0; it < 8; ++it) {
            int idx = it * 256 + tid;               // stage W2^T (128x128)
            int row = idx >> 4, seg = idx & 15;
            short8 v = *(const short8*)(W2T + row * R_ + seg * 8);
            *(short8*)&sW2[row * H1P + seg * 8] = v;
        }
        __syncthreads();

        f32x4 acc2[8][2];
#pragma unroll
        for (int mt = 0; mt < 8; ++mt)
#pragma unroll
            for (int nt = 0; nt < 2; ++nt) acc2[mt][nt] = 0.f;

#pragma unroll
        for (int k2 = 0; k2 < 4; ++k2) {
            const int ko = k2 * 32 + q * 8;
            short8 af[8];
#pragma unroll
            for (int mt = 0; mt < 8; ++mt)
                af[mt] = *(const short8*)&sH1[(mt * 16 + c) * H1P + ko];
#pragma unroll
            for (int nt = 0; nt < 2; ++nt) {
                const int r = w * 32 + nt * 16 + c;
                short8 bf_ = *(const short8*)&sW2[r * H1P + ko];
#pragma unroll
                for (int mt = 0; mt < 8; ++mt)
                    acc2[mt][nt] = __builtin_amdgcn_mfma_f32_16x16x32_bf16(af[mt], bf_, acc2[mt][nt], 0, 0, 0);
            }
        }
#pragma unroll
        for (int nt = 0; nt < 2; ++nt) {
            int r = w * 32 + nt * 16 + c;
            float b2r = b2[r];
            float s = 0.f;
#pragma unroll
            for (int mt = 0; mt < 8; ++mt)
#pragma unroll
                for (int i = 0; i < 4; ++i)
                    s += fast_tanhf(acc2[mt][nt][i] + b2r);
            s += __shfl_xor(s, 16);
            s += __shfl_xor(s, 32);
            if (q == 0) outp[n * R_ + r] = s * (1.f / SEQ_);
        }
    }
}

// ---- pairwise exp(-dist) sums, fp32 register-tiled: block tile 64i x 32j, micro 4x2 ----
__global__ __launch_bounds__(256, 2)
void sim_kernel(const float* __restrict__ pos_t, const float* __restrict__ neg_t,
                double* __restrict__ sims)
{
    __shared__ __align__(16) float sPi[64][132];
    __shared__ __align__(16) float sPj[32][132];
    __shared__ __align__(16) float sNj[32][132];

    const int jb = blockIdx.x;   // 0..63
    const int ib = blockIdx.y;   // 0..31
    const int tid = threadIdx.x;

#pragma unroll
    for (int it = 0; it < 8; ++it) {
        int idx = it * 256 + tid;             // 64 rows x 32 f4
        int row = idx >> 5, seg = idx & 31;
        *(float4*)&sPi[row][seg * 4] = *(const float4*)(pos_t + (ib * 64 + row) * R_ + seg * 4);
    }
#pragma unroll
    for (int it = 0; it < 4; ++it) {
        int idx = it * 256 + tid;             // 32 rows x 32 f4
        int row = idx >> 5, seg = idx & 31;
        *(float4*)&sPj[row][seg * 4] = *(const float4*)(pos_t + (jb * 32 + row) * R_ + seg * 4);
        *(float4*)&sNj[row][seg * 4] = *(const float4*)(neg_t + (jb * 32 + row) * R_ + seg * 4);
    }
    __syncthreads();

    const int ty = tid >> 4, tx = tid & 15;
    float d2p[4][2] = {}, d2n[4][2] = {};

    for (int rr = 0; rr < R_; rr += 4) {
        float4 xi[4], pj[2], nj[2];
#pragma unroll
        for (int a = 0; a < 4; ++a) xi[a] = *(const float4*)&sPi[ty * 4 + a][rr];
#pragma unroll
        for (int b = 0; b < 2; ++b) {
            pj[b] = *(const float4*)&sPj[tx * 2 + b][rr];
            nj[b] = *(const float4*)&sNj[tx * 2 + b][rr];
        }
#pragma unroll
        for (int a = 0; a < 4; ++a)
#pragma unroll
            for (int b = 0; b < 2; ++b) {
                float dx;
                dx = xi[a].x - pj[b].x; d2p[a][b] = fmaf(dx, dx, d2p[a][b]);
                dx = xi[a].y - pj[b].y; d2p[a][b] = fmaf(dx, dx, d2p[a][b]);
                dx = xi[a].z - pj[b].z; d2p[a][b] = fmaf(dx, dx, d2p[a][b]);
                dx = xi[a].w - pj[b].w; d2p[a][b] = fmaf(dx, dx, d2p[a][b]);
                dx = xi[a].x - nj[b].x; d2n[a][b] = fmaf(dx, dx, d2n[a][b]);
                dx = xi[a].y - nj[b].y; d2n[a][b] = fmaf(dx, dx, d2n[a][b]);
                dx = xi[a].z - nj[b].z; d2n[a][b] = fmaf(dx, dx, d2n[a][b]);
                dx = xi[a].w - nj[b].w; d2n[a][b] = fmaf(dx, dx, d2n[a][b]);
            }
    }

    float sp = 0.f, sn = 0.f;
#pragma unroll
    for (int a = 0; a < 4; ++a)
#pragma unroll
        for (int b = 0; b < 2; ++b) {
            sp += __expf(-sqrtf(d2p[a][b]));
            sn += __expf(-sqrtf(d2n[a][b]));
        }

#pragma unroll
    for (int off = 32; off; off >>= 1) {
        sp += __shfl_down(sp, off);
        sn += __shfl_down(sn, off);
    }
    __shared__ double redP[4], redN[4];
    const int wave = tid >> 6, lane = tid & 63;
    if (lane == 0) { redP[wave] = (double)sp; redN[wave] = (double)sn; }
    __syncthreads();
    if (tid == 0) {
        atomicAdd(&sims[0], redP[0] + redP[1] + redP[2] + redP[3]);
        atomicAdd(&sims[1], redN[0] + redN[1] + redN[2] + redN[3]);
    }
}

__global__ void init_kernel(double* __restrict__ sims)
{
    if (threadIdx.x < 2) sims[threadIdx.x] = 0.0;
}

__global__ void finalize_kernel(const double* __restrict__ sims, float* __restrict__ out)
{
    out[N_ * R_] = (float)(-log(sims[0] / sims[1]));
}

extern "C" void kernel_launch(void* const* d_in, const int* in_sizes, int n_in,
                              void* d_out, int out_size, void* d_ws, size_t ws_size,
                              hipStream_t stream)
{
    const int*   C   = (const int*)  d_in[0];
    const float* L   = (const float*)d_in[1];
    const float* Pw  = (const float*)d_in[2];
    const float* Nw  = (const float*)d_in[3];
    const float* W1p = (const float*)d_in[4];
    const float* b1p = (const float*)d_in[5];
    const float* W2p = (const float*)d_in[6];
    const float* b2p = (const float*)d_in[7];
    const float* W1n = (const float*)d_in[8];
    const float* b1n = (const float*)d_in[9];
    const float* W2n = (const float*)d_in[10];
    const float* b2n = (const float*)d_in[11];
    const float* Wa  = (const float*)d_in[12];
    const float* ba  = (const float*)d_in[13];

    float* out   = (float*)d_out;
    float* pos_t = (float*)d_ws;                        // 1 MB
    float* neg_t = pos_t + N_ * R_;                     // 1 MB
    double* sims = (double*)(neg_t + N_ * R_);          // @2 MB
    ushort* WT   = (ushort*)((char*)d_ws + 2 * 1024 * 1024 + 64);  // 448 KB bf16 W^T

    hipLaunchKernelGGL(init_kernel, dim3(1), dim3(64), 0, stream, sims);
    hipLaunchKernelGGL(prep_kernel, dim3(896), dim3(256), 0, stream,
                       W1p, W1n, Wa, W2p, W2n, WT);
    hipLaunchKernelGGL(mlp_mfma_kernel, dim3(N_), dim3(256), 0, stream,
                       C, L, Pw, Nw, b1p, b2p, b1n, b2n, ba, WT, pos_t, neg_t, out);
    hipLaunchKernelGGL(sim_kernel, dim3(64, 32), dim3(256), 0, stream,
                       pos_t, neg_t, sims);
    hipLaunchKernelGGL(finalize_kernel, dim3(1), dim3(1), 0, stream, sims, out);
}

// Round 3
// 888.407 us; speedup vs baseline: 4.3906x; 1.3172x over previous
//
#include <hip/hip_runtime.h>
#include <math.h>

#define N_   2048
#define SEQ_ 128
#define E_   512
#define R_   128
#define NR_  (N_ * R_)

typedef __attribute__((ext_vector_type(8))) short short8;
typedef __attribute__((ext_vector_type(4))) float f32x4;

typedef __attribute__((address_space(3))) void lds_t;
typedef __attribute__((address_space(1))) const void glb_t;

__device__ __forceinline__ void async16(void* l, const void* g) {
    // 16B per lane: LDS dest = uniform base + lane*16; global src per-lane.
    __builtin_amdgcn_global_load_lds((glb_t*)g, (lds_t*)l, 16, 0, 0);
}

__device__ __forceinline__ ushort f2bf(float f) {
    union { float f; uint u; } v; v.f = f;
    uint r = v.u + 0x7FFFu + ((v.u >> 16) & 1u);   // RNE
    return (ushort)(r >> 16);
}
__device__ __forceinline__ float fast_tanhf(float x) {
    float ax = fabsf(x);
    float t = __expf(-2.f * ax);
    float r = (1.f - t) / (1.f + t);
    return copysignf(r, x);
}

// ---- prep: W^T bf16: three ExR -> [128][512]; two RxR -> [128][128] ----
__global__ void prep_kernel(const float* __restrict__ W1p, const float* __restrict__ W1n,
                            const float* __restrict__ Wa,  const float* __restrict__ W2p,
                            const float* __restrict__ W2n, ushort* __restrict__ WT)
{
    int idx = blockIdx.x * 256 + threadIdx.x;      // 0..229375
    if (idx < 196608) {
        int m = idx >> 16;
        int o = idx & 65535;
        int r = o >> 9, e = o & 511;
        const float* src = (m == 0) ? W1p : (m == 1) ? W1n : Wa;
        WT[idx] = f2bf(src[e * R_ + r]);
    } else if (idx < 229376) {
        int o = idx - 196608;
        int m = o >> 14;
        int p = o & 16383;
        int r = p >> 7, e = p & 127;
        const float* src = (m == 0) ? W2p : W2n;
        WT[idx] = f2bf(src[e * R_ + r]);
    }
}

// One block per (n, half): 64 t-rows x 128 r, 4 waves (wave = 32 r-cols).
// XOR swizzle everywhere: 16B seg stored at position seg^(row&7) -> conflict-free,
// unpadded rows -> global_load_lds-compatible.
__global__ __launch_bounds__(256, 2)
void mlp_mfma_kernel(const int* __restrict__ C, const float* __restrict__ L,
                     const float* __restrict__ Pw, const float* __restrict__ Nw,
                     const float* __restrict__ b1p, const float* __restrict__ b2p,
                     const float* __restrict__ b1n, const float* __restrict__ b2n,
                     const float* __restrict__ ba,  const ushort* __restrict__ WT,
                     float* __restrict__ pp, float* __restrict__ nn,
                     float* __restrict__ aa)     // each [2][N][R] partials
{
    __shared__ __align__(16) ushort lds[28672];    // 56 KB
    __shared__ float sPm[64], sNm[64];

    ushort* sX  = lds;             // phase1: [64][64]
    ushort* sW  = lds + 4096;      // phase1: [3][128][64]
    ushort* sH1 = lds;             // phase2: [64][128]
    ushort* sW2 = lds + 8192;      // phase2: [128][128]

    const ushort* W2pT = WT + 196608;
    const ushort* W2nT = WT + 212992;

    const int bid = blockIdx.x;
    const int n = bid >> 1, half = bid & 1;
    const int tid = threadIdx.x;
    const int w = tid >> 6, l = tid & 63, q = l >> 4, c = l & 15;

    if (tid < 64) {
        int tg = half * 64 + tid;
        int c0 = C[2 * n], c1 = C[2 * n + 1];
        bool in = (tg >= c0) && (tg <= c1);
        sPm[tid] = in ? Pw[n * SEQ_ + tg] : 0.f;
        sNm[tid] = in ? 0.f : Nw[n * SEQ_ + tg];
    }

    f32x4 accP[4][2], accN[4][2], accA[4][2];
#pragma unroll
    for (int mt = 0; mt < 4; ++mt)
#pragma unroll
        for (int nt = 0; nt < 2; ++nt) { accP[mt][nt] = 0.f; accN[mt][nt] = 0.f; accA[mt][nt] = 0.f; }

    const float* Lbase = L + ((size_t)n * SEQ_ + half * 64) * E_;

    for (int ch = 0; ch < 8; ++ch) {
        const int kb = ch * 64;
        // X: 64 rows x 64 k fp32 -> bf16, swizzled seg
#pragma unroll
        for (int it = 0; it < 2; ++it) {
            int sidx = it * 256 + tid;         // 512 segs
            int row = sidx >> 3, seg = sidx & 7;
            const float* gp = Lbase + row * E_ + kb + seg * 8;
            float4 v0 = *(const float4*)gp;
            float4 v1 = *(const float4*)(gp + 4);
            union { short8 v; ushort u[8]; } t8;
            t8.u[0] = f2bf(v0.x); t8.u[1] = f2bf(v0.y); t8.u[2] = f2bf(v0.z); t8.u[3] = f2bf(v0.w);
            t8.u[4] = f2bf(v1.x); t8.u[5] = f2bf(v1.y); t8.u[6] = f2bf(v1.z); t8.u[7] = f2bf(v1.w);
            *(short8*)&sX[row * 64 + (seg ^ (row & 7)) * 8] = t8.v;
        }
        // W: 3 sets x 128 rows x 64 k via async DMA, 12 insts/wave
#pragma unroll
        for (int j = 0; j < 12; ++j) {
            int gi = j * 4 + w;                // 0..47
            int s = gi >> 4, blk = gi & 15;
            int row = blk * 8 + (l >> 3);
            int kseg = (l & 7) ^ (row & 7);
            async16(&sW[(s * 128 + blk * 8) * 64], WT + s * 65536 + row * E_ + kb + kseg * 8);
        }
        __syncthreads();

#pragma unroll
        for (int k2 = 0; k2 < 2; ++k2) {
            short8 a[4];
#pragma unroll
            for (int mt = 0; mt < 4; ++mt) {
                int row = mt * 16 + c;
                a[mt] = *(const short8*)&sX[row * 64 + ((k2 * 4 + q) ^ (row & 7)) * 8];
            }
#pragma unroll
            for (int nt = 0; nt < 2; ++nt) {
                int r = w * 32 + nt * 16 + c;
                int p = (k2 * 4 + q) ^ (r & 7);
                short8 bP = *(const short8*)&sW[(0 * 128 + r) * 64 + p * 8];
                short8 bN = *(const short8*)&sW[(1 * 128 + r) * 64 + p * 8];
                short8 bA = *(const short8*)&sW[(2 * 128 + r) * 64 + p * 8];
#pragma unroll
                for (int mt = 0; mt < 4; ++mt) {
                    accP[mt][nt] = __builtin_amdgcn_mfma_f32_16x16x32_bf16(a[mt], bP, accP[mt][nt], 0, 0, 0);
                    accN[mt][nt] = __builtin_amdgcn_mfma_f32_16x16x32_bf16(a[mt], bN, accN[mt][nt], 0, 0, 0);
                    accA[mt][nt] = __builtin_amdgcn_mfma_f32_16x16x32_bf16(a[mt], bA, accA[mt][nt], 0, 0, 0);
                }
            }
        }
        __syncthreads();
    }

    // ---- A-set epilogue -> aa partial ----
#pragma unroll
    for (int nt = 0; nt < 2; ++nt) {
        int r = w * 32 + nt * 16 + c;
        float bar = ba[r];
        float s = 0.f;
#pragma unroll
        for (int mt = 0; mt < 4; ++mt)
#pragma unroll
            for (int i = 0; i < 4; ++i) {
                int t = mt * 16 + q * 4 + i;
                float m = sPm[t] + sNm[t];
                s += fast_tanhf(fmaf(m, accA[mt][nt][i], bar));
            }
        s += __shfl_xor(s, 16);
        s += __shfl_xor(s, 32);
        if (q == 0) aa[half * NR_ + n * R_ + r] = s * (1.f / SEQ_);
    }

    // ---- P then N ----
    for (int ps = 0; ps < 2; ++ps) {
        const f32x4 (*acc1)[2] = ps ? accN : accP;
        const float* sM  = ps ? sNm : sPm;
        const float* b1  = ps ? b1n : b1p;
        const float* b2  = ps ? b2n : b2p;
        const ushort* W2T = ps ? W2nT : W2pT;
        float* outp = ps ? nn : pp;

        __syncthreads();   // prior readers of lds done
#pragma unroll
        for (int nt = 0; nt < 2; ++nt) {
            int r = w * 32 + nt * 16 + c;
            float b1r = b1[r];
            int seg = r >> 3;
#pragma unroll
            for (int mt = 0; mt < 4; ++mt)
#pragma unroll
                for (int i = 0; i < 4; ++i) {
                    int t = mt * 16 + q * 4 + i;
                    float h = fast_tanhf(fmaf(sM[t], acc1[mt][nt][i], b1r));
                    sH1[t * 128 + (seg ^ (t & 7)) * 8 + (r & 7)] = f2bf(h);
                }
        }
        // W2 (128x128) via DMA, 8 insts/wave
#pragma unroll
        for (int j = 0; j < 8; ++j) {
            int gi = j * 4 + w;                // 0..31
            int row = gi * 4 + (l >> 4);
            int kseg = (l & 15) ^ (row & 7);
            async16(&sW2[gi * 512], W2T + row * 128 + kseg * 8);
        }
        __syncthreads();

        f32x4 acc2[4][2];
#pragma unroll
        for (int mt = 0; mt < 4; ++mt)
#pragma unroll
            for (int nt = 0; nt < 2; ++nt) acc2[mt][nt] = 0.f;

#pragma unroll
        for (int k2 = 0; k2 < 4; ++k2) {
            short8 af[4];
#pragma unroll
            for (int mt = 0; mt < 4; ++mt) {
                int row = mt * 16 + c;
                af[mt] = *(const short8*)&sH1[row * 128 + ((k2 * 4 + q) ^ (row & 7)) * 8];
            }
#pragma unroll
            for (int nt = 0; nt < 2; ++nt) {
                int r = w * 32 + nt * 16 + c;
                short8 bf_ = *(const short8*)&sW2[r * 128 + ((k2 * 4 + q) ^ (r & 7)) * 8];
#pragma unroll
                for (int mt = 0; mt < 4; ++mt)
                    acc2[mt][nt] = __builtin_amdgcn_mfma_f32_16x16x32_bf16(af[mt], bf_, acc2[mt][nt], 0, 0, 0);
            }
        }
#pragma unroll
        for (int nt = 0; nt < 2; ++nt) {
            int r = w * 32 + nt * 16 + c;
            float b2r = b2[r];
            float s = 0.f;
#pragma unroll
            for (int mt = 0; mt < 4; ++mt)
#pragma unroll
                for (int i = 0; i < 4; ++i)
                    s += fast_tanhf(acc2[mt][nt][i] + b2r);
            s += __shfl_xor(s, 16);
            s += __shfl_xor(s, 32);
            if (q == 0) outp[half * NR_ + n * R_ + r] = s * (1.f / SEQ_);
        }
    }
}

// ---- combine ff halves -> d_out ----
__global__ __launch_bounds__(256)
void ffcomb_kernel(const float* __restrict__ aa, float* __restrict__ out)
{
    int i = (blockIdx.x * 256 + threadIdx.x) * 4;
    float4 a0 = *(const float4*)(aa + i);
    float4 a1 = *(const float4*)(aa + NR_ + i);
    float4 o; o.x = a0.x + a1.x; o.y = a0.y + a1.y; o.z = a0.z + a1.z; o.w = a0.w + a1.w;
    *(float4*)(out + i) = o;
}

// ---- pairwise exp(-dist): 64i x 32j tile per block, per-block partials (no atomics) ----
__global__ __launch_bounds__(256, 2)
void sim_kernel(const float* __restrict__ pp, const float* __restrict__ nn,
                float* __restrict__ simP, float* __restrict__ simN)
{
    __shared__ __align__(16) float sPi[64][133];
    __shared__ __align__(16) float sPj[32][133];
    __shared__ __align__(16) float sNj[32][133];

    const int jb = blockIdx.x;   // 0..63
    const int ib = blockIdx.y;   // 0..31
    const int tid = threadIdx.x;

#pragma unroll
    for (int it = 0; it < 8; ++it) {
        int idx = it * 256 + tid;
        int row = idx >> 5, seg = idx & 31;
        int g = (ib * 64 + row) * R_ + seg * 4;
        float4 a = *(const float4*)(pp + g);
        float4 b = *(const float4*)(pp + NR_ + g);
        a.x += b.x; a.y += b.y; a.z += b.z; a.w += b.w;
        *(float4*)&sPi[row][seg * 4] = a;
    }
#pragma unroll
    for (int it = 0; it < 4; ++it) {
        int idx = it * 256 + tid;
        int row = idx >> 5, seg = idx & 31;
        int g = (jb * 32 + row) * R_ + seg * 4;
        float4 a = *(const float4*)(pp + g);
        float4 b = *(const float4*)(pp + NR_ + g);
        a.x += b.x; a.y += b.y; a.z += b.z; a.w += b.w;
        *(float4*)&sPj[row][seg * 4] = a;
        float4 u = *(const float4*)(nn + g);
        float4 v = *(const float4*)(nn + NR_ + g);
        u.x += v.x; u.y += v.y; u.z += v.z; u.w += v.w;
        *(float4*)&sNj[row][seg * 4] = u;
    }
    __syncthreads();

    const int ty = tid >> 4, tx = tid & 15;
    float d2p[4][2] = {}, d2n[4][2] = {};

    for (int rr = 0; rr < R_; rr += 4) {
        float4 xi[4], pj[2], nj[2];
#pragma unroll
        for (int a = 0; a < 4; ++a) xi[a] = *(const float4*)&sPi[ty * 4 + a][rr];
#pragma unroll
        for (int b = 0; b < 2; ++b) {
            pj[b] = *(const float4*)&sPj[tx * 2 + b][rr];
            nj[b] = *(const float4*)&sNj[tx * 2 + b][rr];
        }
#pragma unroll
        for (int a = 0; a < 4; ++a)
#pragma unroll
            for (int b = 0; b < 2; ++b) {
                float dx;
                dx = xi[a].x - pj[b].x; d2p[a][b] = fmaf(dx, dx, d2p[a][b]);
                dx = xi[a].y - pj[b].y; d2p[a][b] = fmaf(dx, dx, d2p[a][b]);
                dx = xi[a].z - pj[b].z; d2p[a][b] = fmaf(dx, dx, d2p[a][b]);
                dx = xi[a].w - pj[b].w; d2p[a][b] = fmaf(dx, dx, d2p[a][b]);
                dx = xi[a].x - nj[b].x; d2n[a][b] = fmaf(dx, dx, d2n[a][b]);
                dx = xi[a].y - nj[b].y; d2n[a][b] = fmaf(dx, dx, d2n[a][b]);
                dx = xi[a].z - nj[b].z; d2n[a][b] = fmaf(dx, dx, d2n[a][b]);
                dx = xi[a].w - nj[b].w; d2n[a][b] = fmaf(dx, dx, d2n[a][b]);
            }
    }

    float sp = 0.f, sn = 0.f;
#pragma unroll
    for (int a = 0; a < 4; ++a)
#pragma unroll
        for (int b = 0; b < 2; ++b) {
            sp += __expf(-sqrtf(d2p[a][b]));
            sn += __expf(-sqrtf(d2n[a][b]));
        }

#pragma unroll
    for (int off = 32; off; off >>= 1) {
        sp += __shfl_down(sp, off);
        sn += __shfl_down(sn, off);
    }
    __shared__ float redP[4], redN[4];
    const int wave = tid >> 6, lane = tid & 63;
    if (lane == 0) { redP[wave] = sp; redN[wave] = sn; }
    __syncthreads();
    if (tid == 0) {
        int bidl = ib * 64 + jb;
        simP[bidl] = redP[0] + redP[1] + redP[2] + redP[3];
        simN[bidl] = redN[0] + redN[1] + redN[2] + redN[3];
    }
}

__global__ __launch_bounds__(256)
void finalize_kernel(const float* __restrict__ simP, const float* __restrict__ simN,
                     float* __restrict__ out)
{
    const int tid = threadIdx.x;
    double sp = 0.0, sn = 0.0;
    for (int i = tid; i < 2048; i += 256) { sp += (double)simP[i]; sn += (double)simN[i]; }
    __shared__ double rp[256], rn[256];
    rp[tid] = sp; rn[tid] = sn;
    __syncthreads();
    for (int s = 128; s; s >>= 1) {
        if (tid < s) { rp[tid] += rp[tid + s]; rn[tid] += rn[tid + s]; }
        __syncthreads();
    }
    if (tid == 0) out[NR_] = (float)(-log(rp[0] / rn[0]));
}

extern "C" void kernel_launch(void* const* d_in, const int* in_sizes, int n_in,
                              void* d_out, int out_size, void* d_ws, size_t ws_size,
                              hipStream_t stream)
{
    const int*   C   = (const int*)  d_in[0];
    const float* L   = (const float*)d_in[1];
    const float* Pw  = (const float*)d_in[2];
    const float* Nw  = (const float*)d_in[3];
    const float* W1p = (const float*)d_in[4];
    const float* b1p = (const float*)d_in[5];
    const float* W2p = (const float*)d_in[6];
    const float* b2p = (const float*)d_in[7];
    const float* W1n = (const float*)d_in[8];
    const float* b1n = (const float*)d_in[9];
    const float* W2n = (const float*)d_in[10];
    const float* b2n = (const float*)d_in[11];
    const float* Wa  = (const float*)d_in[12];
    const float* ba  = (const float*)d_in[13];

    float* out = (float*)d_out;
    float* pp  = (float*)d_ws;            // [2][N][R]
    float* nn  = pp + 2 * NR_;            // [2][N][R]
    float* aa  = nn + 2 * NR_;            // [2][N][R]
    float* simP = aa + 2 * NR_;           // [2048]
    float* simN = simP + 2048;            // [2048]
    ushort* WT = (ushort*)((char*)d_ws + 6 * (size_t)NR_ * 4 + 65536);   // 448 KB

    hipLaunchKernelGGL(prep_kernel, dim3(896), dim3(256), 0, stream,
                       W1p, W1n, Wa, W2p, W2n, WT);
    hipLaunchKernelGGL(mlp_mfma_kernel, dim3(2 * N_), dim3(256), 0, stream,
                       C, L, Pw, Nw, b1p, b2p, b1n, b2n, ba, WT, pp, nn, aa);
    hipLaunchKernelGGL(ffcomb_kernel, dim3(NR_ / 1024), dim3(256), 0, stream, aa, out);
    hipLaunchKernelGGL(sim_kernel, dim3(64, 32), dim3(256), 0, stream,
                       pp, nn, simP, simN);
    hipLaunchKernelGGL(finalize_kernel, dim3(1), dim3(256), 0, stream, simP, simN, out);
}